// Round 18
// baseline (100.993 us; speedup 1.0000x reference)
//
#include <hip/hip_runtime.h>

#define E_EDGES 131072
#define N_NODES 4096
#define HOUT    64
#define NE_TOT  (4 * E_EDGES)
#define CAP     256        // per-row slot capacity (mean deg 128, ~11 sigma)
#define CSTRIDE 16         // one cursor per 64B line
#define SC_NBLK 32
#define SC_NTHR 1024
#define SC_EPB  (NE_TOT / SC_NBLK)   // 16384 edges per block
#define SC_EPT  (SC_EPB / SC_NTHR)   // 16 edges per thread

// ---------------------------------------------------------------- bf16 utils
__device__ __forceinline__ unsigned short f2bf(float x) {
    unsigned u = __float_as_uint(x);
    return (unsigned short)((u + 0x7FFFu + ((u >> 16) & 1u)) >> 16);   // RNE
}
__device__ __forceinline__ float bf2f(unsigned b) {
    return __uint_as_float(b << 16);
}

// ---------------------------------------------------------------- helpers
__device__ __forceinline__ void softmax4(const float* __restrict__ cw,
                                         int layer, int c, float f[4]) {
#pragma unroll
    for (int t = 0; t < 4; ++t) f[t] = cw[(layer * 2 + c) * 4 + t];
    float m = fmaxf(fmaxf(f[0], f[1]), fmaxf(f[2], f[3]));
    float s = 0.f;
#pragma unroll
    for (int t = 0; t < 4; ++t) { f[t] = expf(f[t] - m); s += f[t]; }
    float inv = 1.0f / s;
#pragma unroll
    for (int t = 0; t < 4; ++t) f[t] *= inv;
}

__device__ __forceinline__ float selw(const float f[4], int t) {
    float a = (t & 1) ? f[1] : f[0];
    float b = (t & 1) ? f[3] : f[2];
    return (t & 2) ? b : a;
}

__device__ __forceinline__ void fma8(float acc[8], float w, uint4 v) {
    acc[0] += w * bf2f(v.x & 0xFFFFu); acc[1] += w * bf2f(v.x >> 16);
    acc[2] += w * bf2f(v.y & 0xFFFFu); acc[3] += w * bf2f(v.y >> 16);
    acc[4] += w * bf2f(v.z & 0xFFFFu); acc[5] += w * bf2f(v.z >> 16);
    acc[6] += w * bf2f(v.w & 0xFFFFu); acc[7] += w * bf2f(v.w >> 16);
}

__device__ __forceinline__ uint4 pack8(const float acc[8]) {
    uint4 r;
    r.x = (unsigned)f2bf(acc[0]) | ((unsigned)f2bf(acc[1]) << 16);
    r.y = (unsigned)f2bf(acc[2]) | ((unsigned)f2bf(acc[3]) << 16);
    r.z = (unsigned)f2bf(acc[4]) | ((unsigned)f2bf(acc[5]) << 16);
    r.w = (unsigned)f2bf(acc[6]) | ((unsigned)f2bf(acc[7]) << 16);
    return r;
}

// H16 layout: [node][channel][64 bf16]  -> uint index (n*2+c)*32
// Dual-channel wave-level SpMM over one row: 8 edges/step-slot (one per
// 8-lane group), 4x unroll = 32 edges, 8 H-gathers + 4 record loads in
// flight per lane. Records: wbf16<<16 | t<<12 | dst.  (Plain loads --
// H is L2-resident and reused ~128x/pass; NT hints demote it: R16 -4.7us.
// Conv is MSHR-x-latency bound: ~64 fill slots x ~220cy == ~11.4us/pass.)
__device__ __forceinline__ void spmm_row2c(const unsigned* __restrict__ rowe, int len,
                                           const unsigned* __restrict__ H16,
                                           const float f0[4], const float f1[4],
                                           int lane, float a0[8], float a1[8]) {
    int g  = lane >> 3;       // edge slot within step (0..7)
    int hq = lane & 7;        // uint4 slot within the 128B channel row
#pragma unroll
    for (int j = 0; j < 8; ++j) { a0[j] = 0.f; a1[j] = 0.f; }
    int e = 0;
    for (; e + 32 <= len; e += 32) {
        unsigned r0 = rowe[e + g];
        unsigned r1 = rowe[e + 8 + g];
        unsigned r2 = rowe[e + 16 + g];
        unsigned r3 = rowe[e + 24 + g];
        int   d0 = r0 & 0xFFF, t0 = (r0 >> 12) & 3;
        int   d1 = r1 & 0xFFF, t1 = (r1 >> 12) & 3;
        int   d2 = r2 & 0xFFF, t2 = (r2 >> 12) & 3;
        int   d3 = r3 & 0xFFF, t3 = (r3 >> 12) & 3;
        float w0 = bf2f(r0 >> 16), w1 = bf2f(r1 >> 16);
        float w2 = bf2f(r2 >> 16), w3 = bf2f(r3 >> 16);
        uint4 v00 = ((const uint4*)(H16 + (d0 * 2 + 0) * 32))[hq];
        uint4 v01 = ((const uint4*)(H16 + (d0 * 2 + 1) * 32))[hq];
        uint4 v10 = ((const uint4*)(H16 + (d1 * 2 + 0) * 32))[hq];
        uint4 v11 = ((const uint4*)(H16 + (d1 * 2 + 1) * 32))[hq];
        uint4 v20 = ((const uint4*)(H16 + (d2 * 2 + 0) * 32))[hq];
        uint4 v21 = ((const uint4*)(H16 + (d2 * 2 + 1) * 32))[hq];
        uint4 v30 = ((const uint4*)(H16 + (d3 * 2 + 0) * 32))[hq];
        uint4 v31 = ((const uint4*)(H16 + (d3 * 2 + 1) * 32))[hq];
        fma8(a0, w0 * selw(f0, t0), v00);
        fma8(a1, w0 * selw(f1, t0), v01);
        fma8(a0, w1 * selw(f0, t1), v10);
        fma8(a1, w1 * selw(f1, t1), v11);
        fma8(a0, w2 * selw(f0, t2), v20);
        fma8(a1, w2 * selw(f1, t2), v21);
        fma8(a0, w3 * selw(f0, t3), v30);
        fma8(a1, w3 * selw(f1, t3), v31);
    }
    for (; e + 8 <= len; e += 8) {
        unsigned r0 = rowe[e + g];
        int   d0 = r0 & 0xFFF, t0 = (r0 >> 12) & 3;
        float w0 = bf2f(r0 >> 16);
        uint4 v00 = ((const uint4*)(H16 + (d0 * 2 + 0) * 32))[hq];
        uint4 v01 = ((const uint4*)(H16 + (d0 * 2 + 1) * 32))[hq];
        fma8(a0, w0 * selw(f0, t0), v00);
        fma8(a1, w0 * selw(f1, t0), v01);
    }
    if (g < len - e) {
        unsigned r0 = rowe[e + g];
        int   d0 = r0 & 0xFFF, t0 = (r0 >> 12) & 3;
        float w0 = bf2f(r0 >> 16);
        uint4 v00 = ((const uint4*)(H16 + (d0 * 2 + 0) * 32))[hq];
        uint4 v01 = ((const uint4*)(H16 + (d0 * 2 + 1) * 32))[hq];
        fma8(a0, w0 * selw(f0, t0), v00);
        fma8(a1, w0 * selw(f1, t0), v01);
    }
#pragma unroll
    for (int j = 0; j < 8; ++j) {
        a0[j] += __shfl_xor(a0[j], 8);
        a0[j] += __shfl_xor(a0[j], 16);
        a0[j] += __shfl_xor(a0[j], 32);
        a1[j] += __shfl_xor(a1[j], 8);
        a1[j] += __shfl_xor(a1[j], 16);
        a1[j] += __shfl_xor(a1[j], 32);
    }
}

// ----------- LDS-tiled H0 = X @ Ws1 (f32 + interleaved bf16) + cursor zero
// 256 blocks x 256 threads; block = 16 nodes; Ws (66KB, +1 pad) + X tile in LDS.
__global__ void __launch_bounds__(256)
zinit_kernel(const float* __restrict__ X, const float* __restrict__ Ws,
             float* __restrict__ H0, unsigned* __restrict__ H016,
             int* __restrict__ cursor) {
    __shared__ float wsl[2][128][65];     // [c][k][h], +1 pad
    __shared__ float xs[16][128];         // [n_local][k]
    int tid = threadIdx.x;
    int n0  = blockIdx.x * 16;
    cursor[blockIdx.x * 256 + tid] = 0;   // 65536 == N_NODES*CSTRIDE exactly

    // stage Ws: 16384 floats, coalesced global, conflict-free LDS
    for (int i = tid; i < 2 * 128 * 64; i += 256) {
        int c = i >> 13, rem = i & 8191, k = rem >> 6, h = rem & 63;
        wsl[c][k][h] = Ws[i];
    }
    // stage X tile: 512 float4s
    for (int i4 = tid; i4 < 512; i4 += 256) {
        int n = i4 >> 5, kq = i4 & 31;
        ((float4*)xs[n])[kq] = ((const float4*)(X + (n0 + n) * 128))[kq];
    }
    __syncthreads();

    int ch   = tid & 127;
    int c    = ch >> 6, h = ch & 63;
    int ngrp = tid >> 7;                  // 0/1 -> nodes ngrp*8..+7
    float acc[8];
#pragma unroll
    for (int j = 0; j < 8; ++j) acc[j] = 0.f;
#pragma unroll 4
    for (int kq = 0; kq < 32; ++kq) {
        float w0 = wsl[c][kq * 4 + 0][h];
        float w1 = wsl[c][kq * 4 + 1][h];
        float w2 = wsl[c][kq * 4 + 2][h];
        float w3 = wsl[c][kq * 4 + 3][h];
#pragma unroll
        for (int j = 0; j < 8; ++j) {
            float4 x = ((const float4*)xs[ngrp * 8 + j])[kq];
            acc[j] += x.x * w0;           // separate adds: keep k-ascending
            acc[j] += x.y * w1;           // order bit-identical to baseline
            acc[j] += x.z * w2;
            acc[j] += x.w * w3;
        }
    }
#pragma unroll
    for (int j = 0; j < 8; ++j) {
        int n = n0 + ngrp * 8 + j;
        H0[c * (N_NODES * HOUT) + n * HOUT + h] = acc[j];
        ((unsigned short*)H016)[(n * 2 + c) * HOUT + h] = f2bf(acc[j]);
    }
}

// ---- LDS-binned scatter: block = 16384 contiguous edges (half relation t),
//      LDS histogram -> one global atomic per non-empty bin (~128K total,
//      43% fewer than R11) -> reg writes.
__global__ void __launch_bounds__(SC_NTHR)
scatter_kernel(const int* __restrict__ ei, const float* __restrict__ ew,
               int* __restrict__ gcursor, unsigned* __restrict__ edges) {
    __shared__ int shist[N_NODES];
    __shared__ int sbase[N_NODES];
    int tid = threadIdx.x;
    int t   = blockIdx.x >> 3;                       // 8 blocks per relation
    int e0  = (blockIdx.x & 7) * SC_EPB + tid * SC_EPT;
    const int*   ps = ei + (t * 2 + 0) * E_EDGES + e0;
    const int*   pd = ei + (t * 2 + 1) * E_EDGES + e0;
    const float* pw = ew + t * E_EDGES + e0;
#pragma unroll
    for (int j = 0; j < 4; ++j) shist[tid * 4 + j] = 0;
    __syncthreads();

    int   srcs[16];
    int   dsts[16];
    float wts[16];
#pragma unroll
    for (int q = 0; q < 4; ++q) {
        int4   s = ((const int4*)ps)[q];
        int4   d = ((const int4*)pd)[q];
        float4 w = ((const float4*)pw)[q];
        srcs[q * 4 + 0] = s.x; srcs[q * 4 + 1] = s.y;
        srcs[q * 4 + 2] = s.z; srcs[q * 4 + 3] = s.w;
        dsts[q * 4 + 0] = d.x; dsts[q * 4 + 1] = d.y;
        dsts[q * 4 + 2] = d.z; dsts[q * 4 + 3] = d.w;
        wts[q * 4 + 0] = w.x;  wts[q * 4 + 1] = w.y;
        wts[q * 4 + 2] = w.z;  wts[q * 4 + 3] = w.w;
    }
    int lpos[16];
#pragma unroll
    for (int j = 0; j < 16; ++j) lpos[j] = atomicAdd(&shist[srcs[j]], 1);
    __syncthreads();

    // reserve a global range per non-empty bin (4 bins/thread, batched issue)
#pragma unroll
    for (int j = 0; j < 4; ++j) {
        int b = tid * 4 + j;
        int cntb = shist[b];
        if (cntb) sbase[b] = atomicAdd(&gcursor[b * CSTRIDE], cntb);
    }
    __syncthreads();

    unsigned tb = (unsigned)t << 12;
#pragma unroll
    for (int j = 0; j < 16; ++j) {
        unsigned p = (unsigned)(sbase[srcs[j]] + lpos[j]);
        unsigned rec = ((unsigned)f2bf(wts[j]) << 16) | tb | (unsigned)dsts[j];
        if (p < CAP) edges[srcs[j] * CAP + p] = rec;
    }
}

// ---------------------------------------------- layer-0 SpMM, both channels
__global__ void __launch_bounds__(256)
spmm_kernel(const int* __restrict__ cnt, const unsigned* __restrict__ edges,
            const unsigned* __restrict__ Hin16, unsigned* __restrict__ Hout16,
            const float* __restrict__ cw) {
    int row  = (blockIdx.x * 256 + threadIdx.x) >> 6;   // 4096 waves = rows
    int lane = threadIdx.x & 63;
    float f0[4], f1[4];
    softmax4(cw, 0, 0, f0);
    softmax4(cw, 0, 1, f1);
    int len = min(cnt[row * CSTRIDE], CAP);
    float a0[8], a1[8];
    spmm_row2c(edges + row * CAP, len, Hin16, f0, f1, lane, a0, a1);
    if ((lane >> 3) == 0) {
        int hq = lane & 7;
        ((uint4*)(Hout16 + (row * 2 + 0) * 32))[hq] = pack8(a0);
        ((uint4*)(Hout16 + (row * 2 + 1) * 32))[hq] = pack8(a1);
    }
}

// ------- layer-1 SpMM + beta-combine + linear (+ next-FastGTN init)
// 256 threads = 4 waves, one wave per row (both channels in-wave)
template <bool FINAL>
__global__ void __launch_bounds__(256)
tail_kernel(const int* __restrict__ cnt, const unsigned* __restrict__ edges,
            const unsigned* __restrict__ Hin16,   // layer-1 conv input (bf16)
            const float* __restrict__ H0,         // X_ detached init (f32)
            const float* __restrict__ cw,
            const float* __restrict__ lw, const float* __restrict__ lb,
            const float* __restrict__ Wsn,
            float* __restrict__ outp, unsigned* __restrict__ out16) {
    __shared__ float hcomb[4][2 * HOUT];
    __shared__ float mids[4][HOUT];
    int tid  = threadIdx.x;
    int r    = tid >> 6;          // row within block
    int lane = tid & 63;
    int row  = blockIdx.x * 4 + r;

    float f0[4], f1[4];
    softmax4(cw, 1, 0, f0);
    softmax4(cw, 1, 1, f1);
    int len = min(cnt[row * CSTRIDE], CAP);
    float a0[8], a1[8];
    spmm_row2c(edges + row * CAP, len, Hin16, f0, f1, lane, a0, a1);

    // H_ = relu(0.1*X_ + 0.9*H2) for both channels, j = c*64 + h
    if ((lane >> 3) == 0) {
        int hq = lane & 7;
#pragma unroll
        for (int j = 0; j < 8; ++j) {
            int h = hq * 8 + j;
            float h00 = H0[row * HOUT + h];
            float h01 = H0[(N_NODES + row) * HOUT + h];
            hcomb[r][h]        = fmaxf(0.1f * h00 + 0.9f * a0[j], 0.f);
            hcomb[r][HOUT + h] = fmaxf(0.1f * h01 + 0.9f * a1[j], 0.f);
        }
    }
    __syncthreads();

    float a = lb[lane];
#pragma unroll 8
    for (int j = 0; j < 2 * HOUT; ++j) a += hcomb[r][j] * lw[j * HOUT + lane];

    if (FINAL) {
        outp[row * HOUT + lane] = fmaxf(a, 0.f);
    } else {
        mids[r][lane] = fmaxf(a, 0.f);
        __syncthreads();
        // next FastGTN init: H0'[c,row,h] = sum_k mid[k] * Ws_next[c,k,h]
#pragma unroll
        for (int c = 0; c < 2; ++c) {
            float acc = 0.f;
            const float* w = Wsn + c * HOUT * HOUT + lane;
#pragma unroll 8
            for (int k = 0; k < HOUT; ++k) acc += mids[r][k] * w[k * HOUT];
            outp[(c * N_NODES + row) * HOUT + lane] = acc;             // f32 [c][N][64]
            ((unsigned short*)out16)[(row * 2 + c) * HOUT + lane] = f2bf(acc); // interleaved
        }
    }
}

extern "C" void kernel_launch(void* const* d_in, const int* in_sizes, int n_in,
                              void* d_out, int out_size, void* d_ws, size_t ws_size,
                              hipStream_t stream) {
    const int*   ei  = (const int*)d_in[0];
    const float* ew  = (const float*)d_in[1];
    const float* X   = (const float*)d_in[2];
    const float* Ws1 = (const float*)d_in[3];
    const float* cw1 = (const float*)d_in[4];
    const float* lw1 = (const float*)d_in[5];
    const float* lb1 = (const float*)d_in[6];
    const float* Ws2 = (const float*)d_in[7];
    const float* cw2 = (const float*)d_in[8];
    const float* lw2 = (const float*)d_in[9];
    const float* lb2 = (const float*)d_in[10];
    float* outp = (float*)d_out;

    char* ws = (char*)d_ws;
    size_t off = 0;
    auto alloc = [&](size_t bytes) -> void* {
        void* p = ws + off;
        off += (bytes + 255) & ~size_t(255);
        return p;
    };
    int*      cursor = (int*)alloc((size_t)N_NODES * CSTRIDE * 4);
    unsigned* edges  = (unsigned*)alloc((size_t)N_NODES * CAP * 4);
    float*    H0a    = (float*)alloc((size_t)2 * N_NODES * HOUT * 4);
    unsigned* H0a16  = (unsigned*)alloc((size_t)2 * N_NODES * HOUT * 2);
    unsigned* Ha16   = (unsigned*)alloc((size_t)2 * N_NODES * HOUT * 2);
    float*    H0b    = (float*)alloc((size_t)2 * N_NODES * HOUT * 4);
    unsigned* H0b16  = (unsigned*)alloc((size_t)2 * N_NODES * HOUT * 2);

    zinit_kernel  <<<256, 256, 0, stream>>>(X, Ws1, H0a, H0a16, cursor);
    scatter_kernel<<<SC_NBLK, SC_NTHR, 0, stream>>>(ei, ew, cursor, edges);

    // FastGTN #1
    spmm_kernel<<<1024, 256, 0, stream>>>(cursor, edges, H0a16, Ha16, cw1);
    tail_kernel<false><<<1024, 256, 0, stream>>>(
        cursor, edges, Ha16, H0a, cw1, lw1, lb1, Ws2, H0b, H0b16);

    // FastGTN #2
    spmm_kernel<<<1024, 256, 0, stream>>>(cursor, edges, H0b16, Ha16, cw2);
    tail_kernel<true><<<1024, 256, 0, stream>>>(
        cursor, edges, Ha16, H0b, cw2, lw2, lb2, nullptr, outp, nullptr);
}

// Round 19
// 95.853 us; speedup vs baseline: 1.0536x; 1.0536x over previous
//
#include <hip/hip_runtime.h>

#define E_EDGES 131072
#define N_NODES 4096
#define HOUT    64
#define NE_TOT  (4 * E_EDGES)
#define CAP     256        // per-row slot capacity (mean deg 128, ~11 sigma)
#define CSTRIDE 16         // one cursor per 64B line
#define SC_NBLK 64
#define SC_NTHR 1024
#define SC_EPB  (NE_TOT / SC_NBLK)   // 8192 edges per block
#define SC_EPT  (SC_EPB / SC_NTHR)   // 8 edges per thread

// ---------------------------------------------------------------- bf16 utils
__device__ __forceinline__ unsigned short f2bf(float x) {
    unsigned u = __float_as_uint(x);
    return (unsigned short)((u + 0x7FFFu + ((u >> 16) & 1u)) >> 16);   // RNE
}
__device__ __forceinline__ float bf2f(unsigned b) {
    return __uint_as_float(b << 16);
}

// ---------------------------------------------------------------- helpers
__device__ __forceinline__ void softmax4(const float* __restrict__ cw,
                                         int layer, int c, float f[4]) {
#pragma unroll
    for (int t = 0; t < 4; ++t) f[t] = cw[(layer * 2 + c) * 4 + t];
    float m = fmaxf(fmaxf(f[0], f[1]), fmaxf(f[2], f[3]));
    float s = 0.f;
#pragma unroll
    for (int t = 0; t < 4; ++t) { f[t] = expf(f[t] - m); s += f[t]; }
    float inv = 1.0f / s;
#pragma unroll
    for (int t = 0; t < 4; ++t) f[t] *= inv;
}

__device__ __forceinline__ float selw(const float f[4], int t) {
    float a = (t & 1) ? f[1] : f[0];
    float b = (t & 1) ? f[3] : f[2];
    return (t & 2) ? b : a;
}

__device__ __forceinline__ void fma8(float acc[8], float w, uint4 v) {
    acc[0] += w * bf2f(v.x & 0xFFFFu); acc[1] += w * bf2f(v.x >> 16);
    acc[2] += w * bf2f(v.y & 0xFFFFu); acc[3] += w * bf2f(v.y >> 16);
    acc[4] += w * bf2f(v.z & 0xFFFFu); acc[5] += w * bf2f(v.z >> 16);
    acc[6] += w * bf2f(v.w & 0xFFFFu); acc[7] += w * bf2f(v.w >> 16);
}

__device__ __forceinline__ uint4 pack8(const float acc[8]) {
    uint4 r;
    r.x = (unsigned)f2bf(acc[0]) | ((unsigned)f2bf(acc[1]) << 16);
    r.y = (unsigned)f2bf(acc[2]) | ((unsigned)f2bf(acc[3]) << 16);
    r.z = (unsigned)f2bf(acc[4]) | ((unsigned)f2bf(acc[5]) << 16);
    r.w = (unsigned)f2bf(acc[6]) | ((unsigned)f2bf(acc[7]) << 16);
    return r;
}

// H16 layout: [node][channel][64 bf16]  -> uint index (n*2+c)*32
// Dual-channel wave-level SpMM over one row: 8 edges/step-slot (one per
// 8-lane group), 4x unroll = 32 edges, 8 H-gathers + 4 record loads in
// flight per lane. Records: wbf16<<16 | t<<12 | dst.  (Plain loads --
// H is L2-resident and reused ~128x/pass; NT hints demote it: R16 -4.7us.
// Conv is MSHR-x-latency bound: ~64 fill slots x ~220cy == ~11.4us/pass.)
__device__ __forceinline__ void spmm_row2c(const unsigned* __restrict__ rowe, int len,
                                           const unsigned* __restrict__ H16,
                                           const float f0[4], const float f1[4],
                                           int lane, float a0[8], float a1[8]) {
    int g  = lane >> 3;       // edge slot within step (0..7)
    int hq = lane & 7;        // uint4 slot within the 128B channel row
#pragma unroll
    for (int j = 0; j < 8; ++j) { a0[j] = 0.f; a1[j] = 0.f; }
    int e = 0;
    for (; e + 32 <= len; e += 32) {
        unsigned r0 = rowe[e + g];
        unsigned r1 = rowe[e + 8 + g];
        unsigned r2 = rowe[e + 16 + g];
        unsigned r3 = rowe[e + 24 + g];
        int   d0 = r0 & 0xFFF, t0 = (r0 >> 12) & 3;
        int   d1 = r1 & 0xFFF, t1 = (r1 >> 12) & 3;
        int   d2 = r2 & 0xFFF, t2 = (r2 >> 12) & 3;
        int   d3 = r3 & 0xFFF, t3 = (r3 >> 12) & 3;
        float w0 = bf2f(r0 >> 16), w1 = bf2f(r1 >> 16);
        float w2 = bf2f(r2 >> 16), w3 = bf2f(r3 >> 16);
        uint4 v00 = ((const uint4*)(H16 + (d0 * 2 + 0) * 32))[hq];
        uint4 v01 = ((const uint4*)(H16 + (d0 * 2 + 1) * 32))[hq];
        uint4 v10 = ((const uint4*)(H16 + (d1 * 2 + 0) * 32))[hq];
        uint4 v11 = ((const uint4*)(H16 + (d1 * 2 + 1) * 32))[hq];
        uint4 v20 = ((const uint4*)(H16 + (d2 * 2 + 0) * 32))[hq];
        uint4 v21 = ((const uint4*)(H16 + (d2 * 2 + 1) * 32))[hq];
        uint4 v30 = ((const uint4*)(H16 + (d3 * 2 + 0) * 32))[hq];
        uint4 v31 = ((const uint4*)(H16 + (d3 * 2 + 1) * 32))[hq];
        fma8(a0, w0 * selw(f0, t0), v00);
        fma8(a1, w0 * selw(f1, t0), v01);
        fma8(a0, w1 * selw(f0, t1), v10);
        fma8(a1, w1 * selw(f1, t1), v11);
        fma8(a0, w2 * selw(f0, t2), v20);
        fma8(a1, w2 * selw(f1, t2), v21);
        fma8(a0, w3 * selw(f0, t3), v30);
        fma8(a1, w3 * selw(f1, t3), v31);
    }
    for (; e + 8 <= len; e += 8) {
        unsigned r0 = rowe[e + g];
        int   d0 = r0 & 0xFFF, t0 = (r0 >> 12) & 3;
        float w0 = bf2f(r0 >> 16);
        uint4 v00 = ((const uint4*)(H16 + (d0 * 2 + 0) * 32))[hq];
        uint4 v01 = ((const uint4*)(H16 + (d0 * 2 + 1) * 32))[hq];
        fma8(a0, w0 * selw(f0, t0), v00);
        fma8(a1, w0 * selw(f1, t0), v01);
    }
    if (g < len - e) {
        unsigned r0 = rowe[e + g];
        int   d0 = r0 & 0xFFF, t0 = (r0 >> 12) & 3;
        float w0 = bf2f(r0 >> 16);
        uint4 v00 = ((const uint4*)(H16 + (d0 * 2 + 0) * 32))[hq];
        uint4 v01 = ((const uint4*)(H16 + (d0 * 2 + 1) * 32))[hq];
        fma8(a0, w0 * selw(f0, t0), v00);
        fma8(a1, w0 * selw(f1, t0), v01);
    }
#pragma unroll
    for (int j = 0; j < 8; ++j) {
        a0[j] += __shfl_xor(a0[j], 8);
        a0[j] += __shfl_xor(a0[j], 16);
        a0[j] += __shfl_xor(a0[j], 32);
        a1[j] += __shfl_xor(a1[j], 8);
        a1[j] += __shfl_xor(a1[j], 16);
        a1[j] += __shfl_xor(a1[j], 32);
    }
}

// ----------- LDS-tiled H0 = X @ Ws1 (f32 + interleaved bf16) + cursor zero
// 256 blocks x 256 threads; block = 16 nodes; Ws (66KB, +1 pad) + X tile in LDS.
__global__ void __launch_bounds__(256)
zinit_kernel(const float* __restrict__ X, const float* __restrict__ Ws,
             float* __restrict__ H0, unsigned* __restrict__ H016,
             int* __restrict__ cursor) {
    __shared__ float wsl[2][128][65];     // [c][k][h], +1 pad
    __shared__ float xs[16][128];         // [n_local][k]
    int tid = threadIdx.x;
    int n0  = blockIdx.x * 16;
    cursor[blockIdx.x * 256 + tid] = 0;   // 65536 == N_NODES*CSTRIDE exactly

    // stage Ws: 16384 floats, coalesced global, conflict-free LDS
    for (int i = tid; i < 2 * 128 * 64; i += 256) {
        int c = i >> 13, rem = i & 8191, k = rem >> 6, h = rem & 63;
        wsl[c][k][h] = Ws[i];
    }
    // stage X tile: 512 float4s
    for (int i4 = tid; i4 < 512; i4 += 256) {
        int n = i4 >> 5, kq = i4 & 31;
        ((float4*)xs[n])[kq] = ((const float4*)(X + (n0 + n) * 128))[kq];
    }
    __syncthreads();

    int ch   = tid & 127;
    int c    = ch >> 6, h = ch & 63;
    int ngrp = tid >> 7;                  // 0/1 -> nodes ngrp*8..+7
    float acc[8];
#pragma unroll
    for (int j = 0; j < 8; ++j) acc[j] = 0.f;
#pragma unroll 4
    for (int kq = 0; kq < 32; ++kq) {
        float w0 = wsl[c][kq * 4 + 0][h];
        float w1 = wsl[c][kq * 4 + 1][h];
        float w2 = wsl[c][kq * 4 + 2][h];
        float w3 = wsl[c][kq * 4 + 3][h];
#pragma unroll
        for (int j = 0; j < 8; ++j) {
            float4 x = ((const float4*)xs[ngrp * 8 + j])[kq];
            acc[j] += x.x * w0;           // separate adds: keep k-ascending
            acc[j] += x.y * w1;           // order bit-identical to baseline
            acc[j] += x.z * w2;
            acc[j] += x.w * w3;
        }
    }
#pragma unroll
    for (int j = 0; j < 8; ++j) {
        int n = n0 + ngrp * 8 + j;
        H0[c * (N_NODES * HOUT) + n * HOUT + h] = acc[j];
        ((unsigned short*)H016)[(n * 2 + c) * HOUT + h] = f2bf(acc[j]);
    }
}

// ---- LDS-binned scatter: block = 8192 contiguous edges (one relation t),
//      LDS histogram -> one global atomic per non-empty bin -> reg writes.
//      Phase-2 bin order is STAGGERED per block so the 64 blocks don't
//      storm the same cursor lines in lockstep.
__global__ void __launch_bounds__(SC_NTHR)
scatter_kernel(const int* __restrict__ ei, const float* __restrict__ ew,
               int* __restrict__ gcursor, unsigned* __restrict__ edges) {
    __shared__ int shist[N_NODES];
    __shared__ int sbase[N_NODES];
    int tid = threadIdx.x;
    int t   = blockIdx.x >> 4;                       // 16 blocks per relation
    int e0  = (blockIdx.x & 15) * SC_EPB + tid * SC_EPT;
    const int*   ps = ei + (t * 2 + 0) * E_EDGES + e0;
    const int*   pd = ei + (t * 2 + 1) * E_EDGES + e0;
    const float* pw = ew + t * E_EDGES + e0;
#pragma unroll
    for (int j = 0; j < 4; ++j) shist[tid * 4 + j] = 0;
    __syncthreads();

    int4   s0 = ((const int4*)ps)[0],  s1 = ((const int4*)ps)[1];
    int4   d0 = ((const int4*)pd)[0],  d1 = ((const int4*)pd)[1];
    float4 w0 = ((const float4*)pw)[0], w1 = ((const float4*)pw)[1];
    int   srcs[8] = {s0.x, s0.y, s0.z, s0.w, s1.x, s1.y, s1.z, s1.w};
    int   dsts[8] = {d0.x, d0.y, d0.z, d0.w, d1.x, d1.y, d1.z, d1.w};
    float wts[8]  = {w0.x, w0.y, w0.z, w0.w, w1.x, w1.y, w1.z, w1.w};
    int lpos[8];
#pragma unroll
    for (int j = 0; j < 8; ++j) lpos[j] = atomicAdd(&shist[srcs[j]], 1);
    __syncthreads();

    // reserve a global range per non-empty bin (4 bins/thread, batched,
    // block-staggered start to spread same-line contention)
#pragma unroll
    for (int j = 0; j < 4; ++j) {
        int b = (((tid + blockIdx.x * 16) & 1023)) * 4 + j;
        int cntb = shist[b];
        if (cntb) sbase[b] = atomicAdd(&gcursor[b * CSTRIDE], cntb);
    }
    __syncthreads();

    unsigned tb = (unsigned)t << 12;
#pragma unroll
    for (int j = 0; j < 8; ++j) {
        unsigned p = (unsigned)(sbase[srcs[j]] + lpos[j]);
        unsigned rec = ((unsigned)f2bf(wts[j]) << 16) | tb | (unsigned)dsts[j];
        if (p < CAP) edges[srcs[j] * CAP + p] = rec;
    }
}

// ---------------------------------------------- layer-0 SpMM, both channels
__global__ void __launch_bounds__(256)
spmm_kernel(const int* __restrict__ cnt, const unsigned* __restrict__ edges,
            const unsigned* __restrict__ Hin16, unsigned* __restrict__ Hout16,
            const float* __restrict__ cw) {
    int row  = (blockIdx.x * 256 + threadIdx.x) >> 6;   // 4096 waves = rows
    int lane = threadIdx.x & 63;
    float f0[4], f1[4];
    softmax4(cw, 0, 0, f0);
    softmax4(cw, 0, 1, f1);
    int len = min(cnt[row * CSTRIDE], CAP);
    float a0[8], a1[8];
    spmm_row2c(edges + row * CAP, len, Hin16, f0, f1, lane, a0, a1);
    if ((lane >> 3) == 0) {
        int hq = lane & 7;
        ((uint4*)(Hout16 + (row * 2 + 0) * 32))[hq] = pack8(a0);
        ((uint4*)(Hout16 + (row * 2 + 1) * 32))[hq] = pack8(a1);
    }
}

// ------- layer-1 SpMM + beta-combine + linear (+ next-FastGTN init)
// 256 threads = 4 waves, one wave per row (both channels in-wave)
template <bool FINAL>
__global__ void __launch_bounds__(256)
tail_kernel(const int* __restrict__ cnt, const unsigned* __restrict__ edges,
            const unsigned* __restrict__ Hin16,   // layer-1 conv input (bf16)
            const float* __restrict__ H0,         // X_ detached init (f32)
            const float* __restrict__ cw,
            const float* __restrict__ lw, const float* __restrict__ lb,
            const float* __restrict__ Wsn,
            float* __restrict__ outp, unsigned* __restrict__ out16) {
    __shared__ float hcomb[4][2 * HOUT];
    __shared__ float mids[4][HOUT];
    int tid  = threadIdx.x;
    int r    = tid >> 6;          // row within block
    int lane = tid & 63;
    int row  = blockIdx.x * 4 + r;

    float f0[4], f1[4];
    softmax4(cw, 1, 0, f0);
    softmax4(cw, 1, 1, f1);
    int len = min(cnt[row * CSTRIDE], CAP);
    float a0[8], a1[8];
    spmm_row2c(edges + row * CAP, len, Hin16, f0, f1, lane, a0, a1);

    // H_ = relu(0.1*X_ + 0.9*H2) for both channels, j = c*64 + h
    if ((lane >> 3) == 0) {
        int hq = lane & 7;
#pragma unroll
        for (int j = 0; j < 8; ++j) {
            int h = hq * 8 + j;
            float h00 = H0[row * HOUT + h];
            float h01 = H0[(N_NODES + row) * HOUT + h];
            hcomb[r][h]        = fmaxf(0.1f * h00 + 0.9f * a0[j], 0.f);
            hcomb[r][HOUT + h] = fmaxf(0.1f * h01 + 0.9f * a1[j], 0.f);
        }
    }
    __syncthreads();

    float a = lb[lane];
#pragma unroll 8
    for (int j = 0; j < 2 * HOUT; ++j) a += hcomb[r][j] * lw[j * HOUT + lane];

    if (FINAL) {
        outp[row * HOUT + lane] = fmaxf(a, 0.f);
    } else {
        mids[r][lane] = fmaxf(a, 0.f);
        __syncthreads();
        // next FastGTN init: H0'[c,row,h] = sum_k mid[k] * Ws_next[c,k,h]
#pragma unroll
        for (int c = 0; c < 2; ++c) {
            float acc = 0.f;
            const float* w = Wsn + c * HOUT * HOUT + lane;
#pragma unroll 8
            for (int k = 0; k < HOUT; ++k) acc += mids[r][k] * w[k * HOUT];
            outp[(c * N_NODES + row) * HOUT + lane] = acc;             // f32 [c][N][64]
            ((unsigned short*)out16)[(row * 2 + c) * HOUT + lane] = f2bf(acc); // interleaved
        }
    }
}

extern "C" void kernel_launch(void* const* d_in, const int* in_sizes, int n_in,
                              void* d_out, int out_size, void* d_ws, size_t ws_size,
                              hipStream_t stream) {
    const int*   ei  = (const int*)d_in[0];
    const float* ew  = (const float*)d_in[1];
    const float* X   = (const float*)d_in[2];
    const float* Ws1 = (const float*)d_in[3];
    const float* cw1 = (const float*)d_in[4];
    const float* lw1 = (const float*)d_in[5];
    const float* lb1 = (const float*)d_in[6];
    const float* Ws2 = (const float*)d_in[7];
    const float* cw2 = (const float*)d_in[8];
    const float* lw2 = (const float*)d_in[9];
    const float* lb2 = (const float*)d_in[10];
    float* outp = (float*)d_out;

    char* ws = (char*)d_ws;
    size_t off = 0;
    auto alloc = [&](size_t bytes) -> void* {
        void* p = ws + off;
        off += (bytes + 255) & ~size_t(255);
        return p;
    };
    int*      cursor = (int*)alloc((size_t)N_NODES * CSTRIDE * 4);
    unsigned* edges  = (unsigned*)alloc((size_t)N_NODES * CAP * 4);
    float*    H0a    = (float*)alloc((size_t)2 * N_NODES * HOUT * 4);
    unsigned* H0a16  = (unsigned*)alloc((size_t)2 * N_NODES * HOUT * 2);
    unsigned* Ha16   = (unsigned*)alloc((size_t)2 * N_NODES * HOUT * 2);
    float*    H0b    = (float*)alloc((size_t)2 * N_NODES * HOUT * 4);
    unsigned* H0b16  = (unsigned*)alloc((size_t)2 * N_NODES * HOUT * 2);

    zinit_kernel  <<<256, 256, 0, stream>>>(X, Ws1, H0a, H0a16, cursor);
    scatter_kernel<<<SC_NBLK, SC_NTHR, 0, stream>>>(ei, ew, cursor, edges);

    // FastGTN #1
    spmm_kernel<<<1024, 256, 0, stream>>>(cursor, edges, H0a16, Ha16, cw1);
    tail_kernel<false><<<1024, 256, 0, stream>>>(
        cursor, edges, Ha16, H0a, cw1, lw1, lb1, Ws2, H0b, H0b16);

    // FastGTN #2
    spmm_kernel<<<1024, 256, 0, stream>>>(cursor, edges, H0b16, Ha16, cw2);
    tail_kernel<true><<<1024, 256, 0, stream>>>(
        cursor, edges, Ha16, H0b, cw2, lw2, lb2, nullptr, outp, nullptr);
}